// Round 6
// baseline (4476.762 us; speedup 1.0000x reference)
//
#include <hip/hip_runtime.h>

#define TT  128
#define CC  256
#define VV  25
#define KK  3
#define GG  9
#define LL  9
#define NCC 60
#define CINN 3
#define TV    (TT*VV)          // 3200 (input x layout)
#define N4    4096             // padded activation columns: n = t*32+v
#define KDIM2 (CC*GG)          // 2304
#define UR    ((TT+8)*32)      // 4352 Ut2 rows
#define NB    256              // persistent grid size (1 block/CU)

typedef __attribute__((ext_vector_type(8))) short bf16x8;
typedef __attribute__((ext_vector_type(4))) float f32x4;
typedef unsigned short us16;

__device__ __forceinline__ us16 f2bf(float f) {
    union { float f; unsigned u; } a; a.f = f;
    unsigned r = a.u + 0x7fff + ((a.u >> 16) & 1);
    return (us16)(r >> 16);
}
__device__ __forceinline__ bf16x8 ld8(const us16* p) { return *(const bf16x8*)p; }

// ---------------- barrier init ----------------

__global__ void k_init(unsigned* bar) {
    if (threadIdx.x < 16) bar[threadIdx.x] = 0u;
}

// ---------------- merged prep kernel ----------------

#define PN1 (LL*KK*CC*CC)
#define PN2 (LL*CC*CC*GG)
#define PN3 (LL*KK*32*32)
#define PN4 (LL*CC*32)
#define PTOT (PN1+PN2+PN3+PN4)

__global__ void k_prep(const float* __restrict__ Wg, const float* __restrict__ Wt,
                       const float* __restrict__ A, const float* __restrict__ imp,
                       const float* __restrict__ bg,
                       us16* __restrict__ Wgb, us16* __restrict__ Wt2b,
                       us16* __restrict__ AlTb, float* __restrict__ bgAl) {
    int i = blockIdx.x * 256 + threadIdx.x;
    if (i < PN1) {
        Wgb[i] = f2bf(Wg[i]);
    } else if (i < PN1 + PN2) {
        int j = i - PN1;
        int kk = j % (CC*GG);
        int o  = (j / (CC*GG)) % CC;
        int l  = j / (CC*CC*GG);
        int g = kk >> 8, c = kk & 255;
        Wt2b[j] = f2bf(Wt[((size_t)(l*CC + o)*CC + c)*GG + g]);
    } else if (i < PN1 + PN2 + PN3) {
        int j = i - PN1 - PN2;
        int v = j & 31, w = (j >> 5) & 31;
        int lk = j >> 10, k = lk % KK, l = lk / KK;
        float val = 0.f;
        if (v < VV && w < VV)
            val = A[(k*VV+v)*VV + w] * imp[((size_t)(l*KK+k)*VV+v)*VV + w];
        AlTb[j] = f2bf(val);
    } else if (i < PTOT) {
        int j = i - PN1 - PN2 - PN3;
        int w = j & 31, c = (j >> 5) & 255, l = j >> 13;
        float s = 0.f;
        if (w < VV) {
            for (int k = 0; k < KK; k++) {
                float col = 0.f;
                for (int v = 0; v < VV; v++)
                    col += A[(k*VV+v)*VV + w] * imp[((size_t)(l*KK+k)*VV+v)*VV + w];
                s += bg[l*KK*CC + k*CC + c] * col;
            }
        }
        bgAl[j] = s;
    }
}

// ---------------- grid barrier (two-level, agent scope) ----------------

__device__ __forceinline__ void gsync(unsigned* bar) {
    __syncthreads();
    if (threadIdx.x == 0) {
        __threadfence();
        unsigned gen = __hip_atomic_load(bar + 8, __ATOMIC_ACQUIRE, __HIP_MEMORY_SCOPE_AGENT);
        int leaf = blockIdx.x & 7;
        unsigned pos = __hip_atomic_fetch_add(bar + leaf, 1u, __ATOMIC_ACQ_REL, __HIP_MEMORY_SCOPE_AGENT);
        if (pos == (NB/8 - 1)) {
            unsigned done = __hip_atomic_fetch_add(bar + 9, 1u, __ATOMIC_ACQ_REL, __HIP_MEMORY_SCOPE_AGENT);
            if (done == 7u) {
                #pragma unroll
                for (int i = 0; i < 8; i++)
                    __hip_atomic_store(bar + i, 0u, __ATOMIC_RELAXED, __HIP_MEMORY_SCOPE_AGENT);
                __hip_atomic_store(bar + 9, 0u, __ATOMIC_RELAXED, __HIP_MEMORY_SCOPE_AGENT);
                __hip_atomic_fetch_add(bar + 8, 1u, __ATOMIC_ACQ_REL, __HIP_MEMORY_SCOPE_AGENT);
            }
        }
        while (__hip_atomic_load(bar + 8, __ATOMIC_ACQUIRE, __HIP_MEMORY_SCOPE_AGENT) == gen)
            __builtin_amdgcn_s_sleep(1);
        __threadfence();
    }
    __syncthreads();
}

// ---------------- block reduce (sum, sumsq) ----------------

__device__ __forceinline__ void blk_reduce2(float& s, float& q, float* red) {
    #pragma unroll
    for (int off = 32; off; off >>= 1) {
        s += __shfl_down(s, off);
        q += __shfl_down(q, off);
    }
    int lane = threadIdx.x & 63, w = threadIdx.x >> 6;
    if (lane == 0) { red[w] = s; red[4+w] = q; }
    __syncthreads();
    s = red[0]+red[1]+red[2]+red[3];
    q = red[4]+red[5]+red[6]+red[7];
}

// ---------------- the persistent whole-network kernel ----------------

__global__ __launch_bounds__(256) void k_persist(
    const float* __restrict__ x,
    const float* __restrict__ lniw, const float* __restrict__ lnib,
    const float* __restrict__ Win, const float* __restrict__ bin,
    const us16* __restrict__ Wgb_a, const us16* __restrict__ Wt2b_a,
    const us16* __restrict__ AlTb_a, const float* __restrict__ bgAl_a,
    const float* __restrict__ ln1w_a, const float* __restrict__ ln1b_a,
    const float* __restrict__ bt_a, const float* __restrict__ ln2w_a,
    const float* __restrict__ ln2b_a,
    const float* __restrict__ Wout, const float* __restrict__ bout,
    float* __restrict__ H0, float* __restrict__ H1,
    float* __restrict__ TC, us16* __restrict__ Hbt2, us16* __restrict__ Ut2,
    us16* __restrict__ Ybt, float* __restrict__ out, unsigned* bar) {

    const int b = blockIdx.x, tid = threadIdx.x;
    const int wave = tid >> 6, lane = tid & 63, quad = lane >> 4, l16 = lane & 15;
    __shared__ __align__(16) float smem[CC*33];   // 33.8 KB, reused per stage
    __shared__ float red[8];

    // ======== stage 0: LN_in + fcn_in (blocks 0..127) ========
    if (b < TT) {
        int t = b;
        float* sx = smem;
        float* sh = smem + 128;
        if (tid < CINN*VV)
            sx[tid] = x[(size_t)(tid/VV)*TV + t*VV + (tid%VV)];
        __syncthreads();
        float s = 0.f, q = 0.f;
        for (int i = 0; i < CINN*VV; i++) { float v = sx[i]; s += v; q += v*v; }
        float m  = s * (1.f/75.f);
        float var = q * (1.f/75.f) - m*m;
        float rs = rsqrtf(var + 1e-5f);
        if (tid < CINN*VV)
            sh[tid] = (sx[tid]-m)*rs*lniw[tid] + lnib[tid];
        __syncthreads();
        int c = tid;
        float w0 = Win[c*3+0], w1 = Win[c*3+1], w2 = Win[c*3+2], bb = bin[c];
        #pragma unroll
        for (int v = 0; v < VV; v++) {
            float acc = bb + w0*sh[v] + w1*sh[VV+v] + w2*sh[2*VV+v];
            H0[(size_t)c*N4 + t*32 + v] = acc;
            Hbt2[(size_t)(t*32 + v)*CC + c] = f2bf(acc);
        }
        #pragma unroll
        for (int v = VV; v < 32; v++)
            Hbt2[(size_t)(t*32 + v)*CC + c] = 0;
    }
    gsync(bar);

    float* Hin = H0;
    float* Hout = H1;

    for (int l = 0; l < LL; l++) {
        const us16* Wgb  = Wgb_a  + (size_t)l*KK*CC*CC;
        const us16* Wt2  = Wt2b_a + (size_t)l*CC*KDIM2;
        const us16* AlTb = AlTb_a + (size_t)l*KK*32*32;
        const float* bgAl = bgAl_a + (size_t)l*CC*32;
        const float* ln1w = ln1w_a + (size_t)l*CC*VV;
        const float* ln1b = ln1b_a + (size_t)l*CC*VV;
        const float* btl  = bt_a   + (size_t)l*CC;
        const float* ln2w = ln2w_a + (size_t)l*CC*VV;
        const float* ln2b = ln2b_a + (size_t)l*CC*VV;

        // ======== stage 1: GEMM1 Y = Wg@H (768x4096,K=256) -> Ybt, 3 tiles/block ========
        for (int task = b; task < 768; task += NB) {
            int bx = task & 63, by = task >> 6;
            us16* Yl = (us16*)smem;           // 64x72 shorts = 9.2 KB
            __syncthreads();
            const int m0w = by*64 + (wave & 1)*32;
            const int n0w = bx*64 + (wave >> 1)*32;
            const us16* ap = Wgb + (size_t)(m0w + l16)*CC + quad*8;
            const us16* bp = Hbt2 + (size_t)(n0w + l16)*CC + quad*8;
            f32x4 acc[2][2] = {};
            #pragma unroll
            for (int s = 0; s < 8; s++) {
                bf16x8 a0 = ld8(ap + s*32);
                bf16x8 a1 = ld8(ap + s*32 + 16*CC);
                bf16x8 b0 = ld8(bp + s*32);
                bf16x8 b1 = ld8(bp + s*32 + 16*CC);
                acc[0][0] = __builtin_amdgcn_mfma_f32_16x16x32_bf16(a0, b0, acc[0][0], 0,0,0);
                acc[0][1] = __builtin_amdgcn_mfma_f32_16x16x32_bf16(a0, b1, acc[0][1], 0,0,0);
                acc[1][0] = __builtin_amdgcn_mfma_f32_16x16x32_bf16(a1, b0, acc[1][0], 0,0,0);
                acc[1][1] = __builtin_amdgcn_mfma_f32_16x16x32_bf16(a1, b1, acc[1][1], 0,0,0);
            }
            #pragma unroll
            for (int mt = 0; mt < 2; mt++)
                #pragma unroll
                for (int nt = 0; nt < 2; nt++)
                    #pragma unroll
                    for (int r = 0; r < 4; r++) {
                        int m_loc = (wave & 1)*32 + mt*16 + quad*4 + r;
                        int n_loc = (wave >> 1)*32 + nt*16 + l16;
                        Yl[m_loc*72 + n_loc] = f2bf(acc[mt][nt][r]);
                    }
            __syncthreads();
            const int kidx = (by*64) >> 8;
            const int c0   = (by*64) & 255;
            const int t0   = bx*2;
            #pragma unroll
            for (int u = 0; u < 2; u++) {
                int qq = tid*2 + u;
                int ch = qq & 3, row = qq >> 2;
                int cl = row & 63, tl = row >> 6;
                bf16x8 val = *(const bf16x8*)(Yl + cl*72 + tl*32 + ch*8);
                *(bf16x8*)(Ybt + ((size_t)((t0+tl)*CC + c0 + cl))*96 + kidx*32 + ch*8) = val;
            }
        }
        gsync(bar);

        // ======== stage 2: adjacency + LN1 + ReLU -> Ut2 (blocks 0..135) ========
        if (b < TT + 8) {
            int t = b;
            if (t >= TT) {
                int tp = t - TT, c = tid;
                #pragma unroll
                for (int w = 0; w < 32; w++) {
                    float u = (w < VV) ? fmaxf(ln1b[c*VV + w], 0.f) : 0.f;
                    Ut2[(size_t)(tp*32 + w)*CC + c] = f2bf(u);
                }
            } else {
                bf16x8 al[2][3];
                #pragma unroll
                for (int nt = 0; nt < 2; nt++)
                    #pragma unroll
                    for (int s = 0; s < 3; s++)
                        al[nt][s] = ld8(AlTb + (size_t)(s*32 + nt*16 + l16)*32 + quad*8);
                f32x4 z[4][2];
                #pragma unroll
                for (int mt = 0; mt < 4; mt++) { z[mt][0] = (f32x4){}; z[mt][1] = (f32x4){}; }
                #pragma unroll
                for (int mt = 0; mt < 4; mt++) {
                    const us16* yp = Ybt + ((size_t)(t*CC + wave*64 + mt*16 + l16))*96 + quad*8;
                    #pragma unroll
                    for (int s = 0; s < 3; s++) {
                        bf16x8 a = ld8(yp + s*32);
                        z[mt][0] = __builtin_amdgcn_mfma_f32_16x16x32_bf16(a, al[0][s], z[mt][0], 0,0,0);
                        z[mt][1] = __builtin_amdgcn_mfma_f32_16x16x32_bf16(a, al[1][s], z[mt][1], 0,0,0);
                    }
                }
                float s_ = 0.f, q_ = 0.f;
                #pragma unroll
                for (int mt = 0; mt < 4; mt++)
                    #pragma unroll
                    for (int nt = 0; nt < 2; nt++)
                        #pragma unroll
                        for (int r = 0; r < 4; r++) {
                            int c = wave*64 + mt*16 + quad*4 + r;
                            int w = nt*16 + l16;
                            float zb = z[mt][nt][r] + bgAl[c*32 + w];
                            z[mt][nt][r] = zb;
                            if (w < VV) { s_ += zb; q_ += zb*zb; }
                        }
                blk_reduce2(s_, q_, red);
                float m = s_ * (1.f/6400.f);
                float var = q_ * (1.f/6400.f) - m*m;
                float rs = rsqrtf(var + 1e-5f);
                #pragma unroll
                for (int mt = 0; mt < 4; mt++)
                    #pragma unroll
                    for (int nt = 0; nt < 2; nt++) {
                        int w = nt*16 + l16;
                        if (w < VV) {
                            int c0 = wave*64 + mt*16 + quad*4;
                            ushort4 pk;
                            float u0 = fmaxf((z[mt][nt][0]-m)*rs*ln1w[(c0+0)*VV+w] + ln1b[(c0+0)*VV+w], 0.f);
                            float u1 = fmaxf((z[mt][nt][1]-m)*rs*ln1w[(c0+1)*VV+w] + ln1b[(c0+1)*VV+w], 0.f);
                            float u2 = fmaxf((z[mt][nt][2]-m)*rs*ln1w[(c0+2)*VV+w] + ln1b[(c0+2)*VV+w], 0.f);
                            float u3 = fmaxf((z[mt][nt][3]-m)*rs*ln1w[(c0+3)*VV+w] + ln1b[(c0+3)*VV+w], 0.f);
                            pk.x = f2bf(u0); pk.y = f2bf(u1); pk.z = f2bf(u2); pk.w = f2bf(u3);
                            *(ushort4*)(Ut2 + (size_t)((t+8)*32 + w)*CC + c0) = pk;
                        }
                    }
                #pragma unroll
                for (int r = VV; r < 32; r++)
                    Ut2[(size_t)((t+8)*32 + r)*CC + tid] = 0;
            }
        }
        gsync(bar);

        // ======== stage 3: GEMM2 TC = Wt2@Ushift (256x4096,K=2304), 1 tile/block ========
        {
            const int m0w = (b & 3)*64 + (wave & 1)*32;
            const int n0w = (b >> 2)*64 + (wave >> 1)*32;
            const us16* ap = Wt2 + (size_t)(m0w + l16)*KDIM2 + quad*8;
            f32x4 acc00 = {}, acc01 = {}, acc10 = {}, acc11 = {};
            bf16x8 a0, a1, b0, b1;
            auto loadAB = [&](int k0, bf16x8& x0, bf16x8& x1, bf16x8& y0, bf16x8& y1) {
                x0 = ld8(ap + k0);
                x1 = ld8(ap + k0 + 16*KDIM2);
                int g = k0 >> 8;
                const us16* bp = Ut2 + (size_t)(n0w + (8-g)*32 + l16)*CC + (k0 & 255) + quad*8;
                y0 = ld8(bp);
                y1 = ld8(bp + 16*CC);
            };
            loadAB(0, a0, a1, b0, b1);
            #pragma unroll 4
            for (int k0 = 32; k0 < KDIM2; k0 += 32) {
                bf16x8 c0, c1, d0, d1;
                loadAB(k0, c0, c1, d0, d1);
                acc00 = __builtin_amdgcn_mfma_f32_16x16x32_bf16(a0, b0, acc00, 0,0,0);
                acc01 = __builtin_amdgcn_mfma_f32_16x16x32_bf16(a0, b1, acc01, 0,0,0);
                acc10 = __builtin_amdgcn_mfma_f32_16x16x32_bf16(a1, b0, acc10, 0,0,0);
                acc11 = __builtin_amdgcn_mfma_f32_16x16x32_bf16(a1, b1, acc11, 0,0,0);
                a0 = c0; a1 = c1; b0 = d0; b1 = d1;
            }
            acc00 = __builtin_amdgcn_mfma_f32_16x16x32_bf16(a0, b0, acc00, 0,0,0);
            acc01 = __builtin_amdgcn_mfma_f32_16x16x32_bf16(a0, b1, acc01, 0,0,0);
            acc10 = __builtin_amdgcn_mfma_f32_16x16x32_bf16(a1, b0, acc10, 0,0,0);
            acc11 = __builtin_amdgcn_mfma_f32_16x16x32_bf16(a1, b1, acc11, 0,0,0);
            const int r0 = m0w + quad*4;
            const int col = n0w + l16;
            #pragma unroll
            for (int r = 0; r < 4; r++) {
                TC[(size_t)(r0 + r)*N4 + col]           = acc00[r];
                TC[(size_t)(r0 + r)*N4 + col + 16]      = acc01[r];
                TC[(size_t)(r0 + 16 + r)*N4 + col]      = acc10[r];
                TC[(size_t)(r0 + 16 + r)*N4 + col + 16] = acc11[r];
            }
        }
        gsync(bar);

        // ======== stage 4: LN2 + bias + delayed residual + ReLU (blocks 0..127) ========
        if (b < TT) {
            int t = b;
            float* sv = smem;     // CC*33
            #pragma unroll
            for (int j = 0; j < 8; j++) {
                int c = j*32 + (tid >> 3);
                int v4 = (tid & 7) * 4;
                float4 xv = *(const float4*)(TC + (size_t)c*N4 + t*32 + v4);
                sv[c*33 + v4+0] = xv.x; sv[c*33 + v4+1] = xv.y;
                sv[c*33 + v4+2] = xv.z; sv[c*33 + v4+3] = xv.w;
            }
            __syncthreads();
            int c = tid;
            float btc = btl[c];
            float vals[VV];
            float s = 0.f, q = 0.f;
            #pragma unroll
            for (int v = 0; v < VV; v++) {
                float xv = sv[c*33 + v] + btc;
                vals[v] = xv; s += xv; q += xv*xv;
            }
            blk_reduce2(s, q, red);
            float m = s * (1.f/6400.f);
            float var = q * (1.f/6400.f) - m*m;
            float rs = rsqrtf(var + 1e-5f);
            #pragma unroll
            for (int v = 0; v < VV; v++) {
                float res = (t >= 4) ? Hin[(size_t)c*N4 + (t-4)*32 + v] : 0.f;
                float o = fmaxf((vals[v]-m)*rs*ln2w[c*VV+v] + ln2b[c*VV+v] + res, 0.f);
                Hout[(size_t)c*N4 + t*32 + v] = o;
                sv[c*33 + v] = o;
            }
            __syncthreads();
            #pragma unroll
            for (int v = 0; v < VV; v++)
                Hbt2[(size_t)(t*32 + v)*CC + tid] = f2bf(sv[tid*33 + v]);
            #pragma unroll
            for (int v = VV; v < 32; v++)
                Hbt2[(size_t)(t*32 + v)*CC + tid] = 0;
        }
        gsync(bar);

        float* tmp = Hin; Hin = Hout; Hout = tmp;
    }

    // ======== classifier (blocks 0..127) ========
    if (b < TT) {
        int t = b;
        float* sp = smem;
        float s = 0.f;
        for (int v = 0; v < VV; v++) s += Hin[(size_t)tid*N4 + t*32 + v];
        sp[tid] = s * (1.f/VV);
        __syncthreads();
        if (tid < NCC) {
            float acc = bout[tid];
            for (int c = 0; c < CC; c++) acc = fmaf(Wout[tid*CC+c], sp[c], acc);
            out[t*NCC + tid] = acc;
        }
    }
}

// ---------------- launch ----------------

extern "C" void kernel_launch(void* const* d_in, const int* in_sizes, int n_in,
                              void* d_out, int out_size, void* d_ws, size_t ws_size,
                              hipStream_t stream) {
    const float* x    = (const float*)d_in[0];
    const float* A    = (const float*)d_in[1];
    const float* lniw = (const float*)d_in[2];
    const float* lnib = (const float*)d_in[3];
    const float* Win  = (const float*)d_in[4];
    const float* bin  = (const float*)d_in[5];
    const float* Wg   = (const float*)d_in[6];
    const float* bg   = (const float*)d_in[7];
    const float* ln1w = (const float*)d_in[8];
    const float* ln1b = (const float*)d_in[9];
    const float* Wt   = (const float*)d_in[10];
    const float* bt   = (const float*)d_in[11];
    const float* ln2w = (const float*)d_in[12];
    const float* ln2b = (const float*)d_in[13];
    const float* imp  = (const float*)d_in[14];
    const float* Wout = (const float*)d_in[15];
    const float* bout = (const float*)d_in[16];
    float* out = (float*)d_out;

    float* ws = (float*)d_ws;
    size_t off = 0;
    auto alloc = [&](size_t n) { float* p = ws + off; off += (n + 255) & ~(size_t)255; return p; };
    float* H0   = alloc((size_t)CC*N4);
    float* H1   = alloc((size_t)CC*N4);
    float* TC   = alloc((size_t)CC*N4);
    float* bgAl = alloc((size_t)LL*CC*32);
    unsigned* bar = (unsigned*)alloc(256);
    us16* Wgb  = (us16*)alloc((size_t)LL*KK*CC*CC/2);
    us16* Wt2b = (us16*)alloc((size_t)LL*CC*KDIM2/2);
    us16* Hbt2 = (us16*)alloc((size_t)N4*CC/2);
    us16* Ut2  = (us16*)alloc((size_t)UR*CC/2);
    us16* AlTb = (us16*)alloc((size_t)LL*KK*32*32/2);
    us16* Ybt  = (us16*)alloc((size_t)TT*CC*96/2);
    (void)ws_size; (void)in_sizes; (void)n_in; (void)out_size;

    k_init<<<1, 64, 0, stream>>>(bar);
    k_prep<<<(PTOT + 255)/256, 256, 0, stream>>>(Wg, Wt, A, imp, bg,
                                                 Wgb, Wt2b, AlTb, bgAl);
    k_persist<<<NB, 256, 0, stream>>>(
        x, lniw, lnib, Win, bin,
        Wgb, Wt2b, AlTb, bgAl,
        ln1w, ln1b, bt, ln2w, ln2b,
        Wout, bout,
        H0, H1, TC, Hbt2, Ut2, Ybt, out, bar);
}

// Round 7
// 1128.137 us; speedup vs baseline: 3.9683x; 3.9683x over previous
//
#include <hip/hip_runtime.h>

#define TT  128
#define CC  256
#define VV  25
#define KK  3
#define GG  9
#define LL  9
#define NCC 60
#define CINN 3
#define TV    (TT*VV)          // 3200 (input x layout)
#define N4    4096             // padded activation columns: n = t*32+v
#define KDIM2 (CC*GG)          // 2304
#define UR    ((TT+8)*32)      // 4352 Ut2 rows
#define BSTR  264              // LDS B-tile row stride (shorts): 528B, +4-bank skew
#define FSTR  33               // LDS fp32 stage row stride

typedef __attribute__((ext_vector_type(8))) short bf16x8;
typedef __attribute__((ext_vector_type(4))) float f32x4;
typedef unsigned short us16;

__device__ __forceinline__ us16 f2bf(float f) {
    union { float f; unsigned u; } a; a.f = f;
    unsigned r = a.u + 0x7fff + ((a.u >> 16) & 1);
    return (us16)(r >> 16);
}
__device__ __forceinline__ bf16x8 ld8(const us16* p) { return *(const bf16x8*)p; }

// ---------------- merged prep kernel ----------------

#define PN1 (LL*KK*CC*CC)
#define PN2 (LL*CC*CC*GG)
#define PN3 (LL*KK*32*32)
#define PN4 (LL*CC*32)
#define PTOT (PN1+PN2+PN3+PN4)

__global__ void k_prep(const float* __restrict__ Wg, const float* __restrict__ Wt,
                       const float* __restrict__ A, const float* __restrict__ imp,
                       const float* __restrict__ bg,
                       us16* __restrict__ Wgb, us16* __restrict__ Wt2b,
                       us16* __restrict__ AlTb, float* __restrict__ bgAl) {
    int i = blockIdx.x * 256 + threadIdx.x;
    if (i < PN1) {
        Wgb[i] = f2bf(Wg[i]);
    } else if (i < PN1 + PN2) {
        int j = i - PN1;
        int kk = j % (CC*GG);
        int o  = (j / (CC*GG)) % CC;
        int l  = j / (CC*CC*GG);
        int g = kk >> 8, c = kk & 255;
        Wt2b[j] = f2bf(Wt[((size_t)(l*CC + o)*CC + c)*GG + g]);
    } else if (i < PN1 + PN2 + PN3) {
        int j = i - PN1 - PN2;
        int v = j & 31, w = (j >> 5) & 31;
        int lk = j >> 10, k = lk % KK, l = lk / KK;
        float val = 0.f;
        if (v < VV && w < VV)
            val = A[(k*VV+v)*VV + w] * imp[((size_t)(l*KK+k)*VV+v)*VV + w];
        AlTb[j] = f2bf(val);
    } else if (i < PTOT) {
        int j = i - PN1 - PN2 - PN3;
        int w = j & 31, c = (j >> 5) & 255, l = j >> 13;
        float s = 0.f;
        if (w < VV) {
            for (int k = 0; k < KK; k++) {
                float col = 0.f;
                for (int v = 0; v < VV; v++)
                    col += A[(k*VV+v)*VV + w] * imp[((size_t)(l*KK+k)*VV+v)*VV + w];
                s += bg[l*KK*CC + k*CC + c] * col;
            }
        }
        bgAl[j] = s;
    }
}

// ---------------- input stage: LN_in + fcn_in -> HT (fp32 transposed) + Hbt2 ----------------

__global__ __launch_bounds__(256) void k_h0(const float* __restrict__ x,
                                            const float* __restrict__ lnw,
                                            const float* __restrict__ lnb,
                                            const float* __restrict__ Win,
                                            const float* __restrict__ bin,
                                            float* __restrict__ HT,
                                            us16* __restrict__ Hbt2) {
    int t = blockIdx.x, tid = threadIdx.x;
    __shared__ float sx[CINN*VV];
    __shared__ float sh[CINN*VV];
    if (tid < CINN*VV)
        sx[tid] = x[(size_t)(tid/VV)*TV + t*VV + (tid%VV)];
    __syncthreads();
    float s = 0.f, q = 0.f;
    for (int i = 0; i < CINN*VV; i++) { float v = sx[i]; s += v; q += v*v; }
    float m  = s * (1.f/75.f);
    float var = q * (1.f/75.f) - m*m;
    float rs = rsqrtf(var + 1e-5f);
    if (tid < CINN*VV)
        sh[tid] = (sx[tid]-m)*rs*lnw[tid] + lnb[tid];
    __syncthreads();
    int c = tid;
    float w0 = Win[c*3+0], w1 = Win[c*3+1], w2 = Win[c*3+2], b = bin[c];
    #pragma unroll
    for (int v = 0; v < VV; v++) {
        float acc = b + w0*sh[v] + w1*sh[VV+v] + w2*sh[2*VV+v];
        HT[(size_t)(t*32 + v)*CC + c] = acc;
        Hbt2[(size_t)(t*32 + v)*CC + c] = f2bf(acc);
    }
    #pragma unroll
    for (int v = VV; v < 32; v++)
        Hbt2[(size_t)(t*32 + v)*CC + c] = 0;
}

// ---------------- block reduce (sum, sumsq) ----------------

__device__ __forceinline__ void blk_reduce2(float& s, float& q, float* red) {
    #pragma unroll
    for (int off = 32; off; off >>= 1) {
        s += __shfl_down(s, off);
        q += __shfl_down(q, off);
    }
    int lane = threadIdx.x & 63, w = threadIdx.x >> 6;
    if (lane == 0) { red[w] = s; red[4+w] = q; }
    __syncthreads();
    s = red[0]+red[1]+red[2]+red[3];
    q = red[4]+red[5]+red[6]+red[7];
}

// ---------------- GEMM1 (optionally fused with previous layer's LN2) ----------------
// FLN=0: B from global Hbt2.  FLN=1: compute h_l = relu(LN2(TC+bt)+res) for this
// block's 2 frames into LDS (bf16, B-operand layout), write HnextT once (by==0).

template<int FLN>
__global__ __launch_bounds__(256) void k_gemm1(const us16* __restrict__ A,
                                               const us16* __restrict__ Bt,
                                               const float* __restrict__ TC,
                                               const float* __restrict__ HprevT,
                                               const float* __restrict__ lnw,
                                               const float* __restrict__ lnb,
                                               const float* __restrict__ btv,
                                               float* __restrict__ HnextT,
                                               us16* __restrict__ Ybt) {
    __shared__ __align__(16) float sF[CC*FSTR];    // fp32 stage / Yl overlay
    __shared__ __align__(16) us16 sB[64*BSTR];     // bf16 B tile (FLN)
    __shared__ float red[8];
    const int tid = threadIdx.x;
    const int wave = tid >> 6, lane = tid & 63, quad = lane >> 4, l16 = lane & 15;
    const int bx = blockIdx.x, by = blockIdx.y;

    if (FLN) {
        const int t0 = bx*2;
        const int c = tid;
        const float btc = btv[c];
        #pragma unroll
        for (int f = 0; f < 2; f++) {
            const int t = t0 + f;
            // coalesced stage of the frame's 256x32 TC slab
            #pragma unroll
            for (int j = 0; j < 8; j++) {
                int cs = j*32 + (tid >> 3);
                int v4 = (tid & 7) * 4;
                float4 xv = *(const float4*)(TC + (size_t)cs*N4 + t*32 + v4);
                sF[cs*FSTR + v4+0] = xv.x; sF[cs*FSTR + v4+1] = xv.y;
                sF[cs*FSTR + v4+2] = xv.z; sF[cs*FSTR + v4+3] = xv.w;
            }
            __syncthreads();
            float vals[VV];
            float s = 0.f, q = 0.f;
            #pragma unroll
            for (int v = 0; v < VV; v++) {
                float xv = sF[c*FSTR + v] + btc;
                vals[v] = xv; s += xv; q += xv*xv;
            }
            blk_reduce2(s, q, red);
            float m = s * (1.f/6400.f);
            float var = q * (1.f/6400.f) - m*m;
            float rs = rsqrtf(var + 1e-5f);
            #pragma unroll
            for (int v = 0; v < VV; v++) {
                float res = (t >= 4) ? HprevT[(size_t)((t-4)*32 + v)*CC + c] : 0.f;
                float o = fmaxf((vals[v]-m)*rs*lnw[c*VV+v] + lnb[c*VV+v] + res, 0.f);
                if (by == 0) HnextT[(size_t)(t*32 + v)*CC + c] = o;
                sB[(f*32 + v)*BSTR + c] = f2bf(o);
            }
            #pragma unroll
            for (int v = VV; v < 32; v++)
                sB[(f*32 + v)*BSTR + c] = 0;
            __syncthreads();
        }
    }

    // ---- MFMA: 64x64 tile of Y = Wg @ H ----
    const int m0w = by*64 + (wave & 1)*32;
    const us16* ap = A + (size_t)(m0w + l16)*CC + quad*8;
    f32x4 acc[2][2] = {};
    if (FLN) {
        const int nl = (wave >> 1)*32 + l16;
        #pragma unroll
        for (int s = 0; s < 8; s++) {
            bf16x8 a0 = ld8(ap + s*32);
            bf16x8 a1 = ld8(ap + s*32 + 16*CC);
            bf16x8 b0 = *(const bf16x8*)(sB + (size_t)nl*BSTR + s*32 + quad*8);
            bf16x8 b1 = *(const bf16x8*)(sB + (size_t)(nl+16)*BSTR + s*32 + quad*8);
            acc[0][0] = __builtin_amdgcn_mfma_f32_16x16x32_bf16(a0, b0, acc[0][0], 0,0,0);
            acc[0][1] = __builtin_amdgcn_mfma_f32_16x16x32_bf16(a0, b1, acc[0][1], 0,0,0);
            acc[1][0] = __builtin_amdgcn_mfma_f32_16x16x32_bf16(a1, b0, acc[1][0], 0,0,0);
            acc[1][1] = __builtin_amdgcn_mfma_f32_16x16x32_bf16(a1, b1, acc[1][1], 0,0,0);
        }
    } else {
        const int n0w = bx*64 + (wave >> 1)*32;
        const us16* bp = Bt + (size_t)(n0w + l16)*CC + quad*8;
        #pragma unroll
        for (int s = 0; s < 8; s++) {
            bf16x8 a0 = ld8(ap + s*32);
            bf16x8 a1 = ld8(ap + s*32 + 16*CC);
            bf16x8 b0 = ld8(bp + s*32);
            bf16x8 b1 = ld8(bp + s*32 + 16*CC);
            acc[0][0] = __builtin_amdgcn_mfma_f32_16x16x32_bf16(a0, b0, acc[0][0], 0,0,0);
            acc[0][1] = __builtin_amdgcn_mfma_f32_16x16x32_bf16(a0, b1, acc[0][1], 0,0,0);
            acc[1][0] = __builtin_amdgcn_mfma_f32_16x16x32_bf16(a1, b0, acc[1][0], 0,0,0);
            acc[1][1] = __builtin_amdgcn_mfma_f32_16x16x32_bf16(a1, b1, acc[1][1], 0,0,0);
        }
    }
    // ---- epilogue: repack to Ybt[t][c][k*32+v] via LDS (Yl overlays sF) ----
    __syncthreads();
    us16* Yl = (us16*)sF;
    #pragma unroll
    for (int mt = 0; mt < 2; mt++)
        #pragma unroll
        for (int nt = 0; nt < 2; nt++)
            #pragma unroll
            for (int r = 0; r < 4; r++) {
                int m_loc = (wave & 1)*32 + mt*16 + quad*4 + r;
                int n_loc = (wave >> 1)*32 + nt*16 + l16;
                Yl[m_loc*72 + n_loc] = f2bf(acc[mt][nt][r]);
            }
    __syncthreads();
    const int kidx = (by*64) >> 8;
    const int c0   = (by*64) & 255;
    const int t0s  = bx*2;
    #pragma unroll
    for (int u = 0; u < 2; u++) {
        int qq = tid*2 + u;
        int ch = qq & 3, row = qq >> 2;
        int cl = row & 63, tl = row >> 6;
        bf16x8 val = *(const bf16x8*)(Yl + cl*72 + tl*32 + ch*8);
        *(bf16x8*)(Ybt + ((size_t)((t0s+tl)*CC + c0 + cl))*96 + kidx*32 + ch*8) = val;
    }
}

// ---------------- adjacency (MFMA, M=256 N=32 K=96) + LN1 + ReLU -> Ut2 ----------------

__global__ __launch_bounds__(256) void k_adj(const us16* __restrict__ Ybt,
                                             const us16* __restrict__ AlTb,
                                             const float* __restrict__ bgAl,
                                             const float* __restrict__ lnw,
                                             const float* __restrict__ lnb,
                                             us16* __restrict__ Ut2) {
    int t = blockIdx.x, tid = threadIdx.x;
    if (t >= TT) {                    // 8 history pad frames
        int tp = t - TT, c = tid;
        #pragma unroll
        for (int w = 0; w < 32; w++) {
            float u = (w < VV) ? fmaxf(lnb[c*VV + w], 0.f) : 0.f;
            Ut2[(size_t)(tp*32 + w)*CC + c] = f2bf(u);
        }
        return;
    }
    __shared__ float red[8];
    const int wave = tid >> 6, lane = tid & 63, quad = lane >> 4, l16 = lane & 15;
    bf16x8 al[2][3];
    #pragma unroll
    for (int nt = 0; nt < 2; nt++)
        #pragma unroll
        for (int s = 0; s < 3; s++)
            al[nt][s] = ld8(AlTb + (size_t)(s*32 + nt*16 + l16)*32 + quad*8);
    f32x4 z[4][2];
    #pragma unroll
    for (int mt = 0; mt < 4; mt++) { z[mt][0] = (f32x4){}; z[mt][1] = (f32x4){}; }
    #pragma unroll
    for (int mt = 0; mt < 4; mt++) {
        const us16* yp = Ybt + ((size_t)(t*CC + wave*64 + mt*16 + l16))*96 + quad*8;
        #pragma unroll
        for (int s = 0; s < 3; s++) {
            bf16x8 a = ld8(yp + s*32);
            z[mt][0] = __builtin_amdgcn_mfma_f32_16x16x32_bf16(a, al[0][s], z[mt][0], 0,0,0);
            z[mt][1] = __builtin_amdgcn_mfma_f32_16x16x32_bf16(a, al[1][s], z[mt][1], 0,0,0);
        }
    }
    float s_ = 0.f, q_ = 0.f;
    #pragma unroll
    for (int mt = 0; mt < 4; mt++)
        #pragma unroll
        for (int nt = 0; nt < 2; nt++)
            #pragma unroll
            for (int r = 0; r < 4; r++) {
                int c = wave*64 + mt*16 + quad*4 + r;
                int w = nt*16 + l16;
                float zb = z[mt][nt][r] + bgAl[c*32 + w];
                z[mt][nt][r] = zb;
                if (w < VV) { s_ += zb; q_ += zb*zb; }
            }
    blk_reduce2(s_, q_, red);
    float m = s_ * (1.f/6400.f);
    float var = q_ * (1.f/6400.f) - m*m;
    float rs = rsqrtf(var + 1e-5f);
    #pragma unroll
    for (int mt = 0; mt < 4; mt++)
        #pragma unroll
        for (int nt = 0; nt < 2; nt++) {
            int w = nt*16 + l16;
            if (w < VV) {
                int c0 = wave*64 + mt*16 + quad*4;
                ushort4 pk;
                float u0 = fmaxf((z[mt][nt][0]-m)*rs*lnw[(c0+0)*VV+w] + lnb[(c0+0)*VV+w], 0.f);
                float u1 = fmaxf((z[mt][nt][1]-m)*rs*lnw[(c0+1)*VV+w] + lnb[(c0+1)*VV+w], 0.f);
                float u2 = fmaxf((z[mt][nt][2]-m)*rs*lnw[(c0+2)*VV+w] + lnb[(c0+2)*VV+w], 0.f);
                float u3 = fmaxf((z[mt][nt][3]-m)*rs*lnw[(c0+3)*VV+w] + lnb[(c0+3)*VV+w], 0.f);
                pk.x = f2bf(u0); pk.y = f2bf(u1); pk.z = f2bf(u2); pk.w = f2bf(u3);
                *(ushort4*)(Ut2 + (size_t)((t+8)*32 + w)*CC + c0) = pk;
            }
        }
    #pragma unroll
    for (int r = VV; r < 32; r++)
        Ut2[(size_t)((t+8)*32 + r)*CC + tid] = 0;
}

// ---------------- GEMM2: TC = Wt2 @ Ushift (256x4096, K=2304), depth-2 pipeline ----------------

__global__ __launch_bounds__(256) void k_gemm2(const us16* __restrict__ A,
                                               const us16* __restrict__ Ut2,
                                               float* __restrict__ TC) {
    const int tid = threadIdx.x;
    const int wave = tid >> 6, lane = tid & 63, quad = lane >> 4, l16 = lane & 15;
    const int m0w = blockIdx.y * 64 + (wave & 1) * 32;
    const int n0w = blockIdx.x * 64 + (wave >> 1) * 32;
    const us16* ap = A + (size_t)(m0w + l16) * KDIM2 + quad * 8;
    f32x4 acc00 = {}, acc01 = {}, acc10 = {}, acc11 = {};
    bf16x8 a0[2], a1[2], b0[2], b1[2];

    auto loadAB = [&](int k0, bf16x8& x0, bf16x8& x1, bf16x8& y0, bf16x8& y1) {
        x0 = ld8(ap + k0);
        x1 = ld8(ap + k0 + 16*KDIM2);
        int g = k0 >> 8;
        const us16* bp = Ut2 + (size_t)(n0w + (8-g)*32 + l16)*CC + (k0 & 255) + quad*8;
        y0 = ld8(bp);
        y1 = ld8(bp + 16*CC);
    };
    auto domfma = [&](bf16x8 x0, bf16x8 x1, bf16x8 y0, bf16x8 y1) {
        acc00 = __builtin_amdgcn_mfma_f32_16x16x32_bf16(x0, y0, acc00, 0,0,0);
        acc01 = __builtin_amdgcn_mfma_f32_16x16x32_bf16(x0, y1, acc01, 0,0,0);
        acc10 = __builtin_amdgcn_mfma_f32_16x16x32_bf16(x1, y0, acc10, 0,0,0);
        acc11 = __builtin_amdgcn_mfma_f32_16x16x32_bf16(x1, y1, acc11, 0,0,0);
    };

    loadAB(0,  a0[0], a1[0], b0[0], b1[0]);
    loadAB(32, a0[1], a1[1], b0[1], b1[1]);
    #pragma unroll 2
    for (int k0 = 64; k0 < KDIM2; k0 += 32) {
        int sl = (k0 >> 5) & 1;
        bf16x8 ta0 = a0[sl], ta1 = a1[sl], tb0 = b0[sl], tb1 = b1[sl];
        loadAB(k0, a0[sl], a1[sl], b0[sl], b1[sl]);
        domfma(ta0, ta1, tb0, tb1);
    }
    domfma(a0[0], a1[0], b0[0], b1[0]);
    domfma(a0[1], a1[1], b0[1], b1[1]);

    const int r0 = m0w + quad*4;
    const int col = n0w + l16;
    #pragma unroll
    for (int r = 0; r < 4; r++) {
        TC[(size_t)(r0 + r)*N4 + col]           = acc00[r];
        TC[(size_t)(r0 + r)*N4 + col + 16]      = acc01[r];
        TC[(size_t)(r0 + 16 + r)*N4 + col]      = acc10[r];
        TC[(size_t)(r0 + 16 + r)*N4 + col + 16] = acc11[r];
    }
}

// ---------------- final LN2 + residual + ReLU + pool + classifier ----------------

__global__ __launch_bounds__(256) void k_out(const float* __restrict__ TC,
                                             const float* __restrict__ HT,
                                             const float* __restrict__ btv,
                                             const float* __restrict__ lnw,
                                             const float* __restrict__ lnb,
                                             const float* __restrict__ Wout,
                                             const float* __restrict__ bout,
                                             float* __restrict__ out) {
    int t = blockIdx.x, tid = threadIdx.x;
    __shared__ float sF[CC*FSTR];
    __shared__ float red[8];
    __shared__ float sp[CC];
    #pragma unroll
    for (int j = 0; j < 8; j++) {
        int cs = j*32 + (tid >> 3);
        int v4 = (tid & 7) * 4;
        float4 xv = *(const float4*)(TC + (size_t)cs*N4 + t*32 + v4);
        sF[cs*FSTR + v4+0] = xv.x; sF[cs*FSTR + v4+1] = xv.y;
        sF[cs*FSTR + v4+2] = xv.z; sF[cs*FSTR + v4+3] = xv.w;
    }
    __syncthreads();
    int c = tid;
    float btc = btv[c];
    float vals[VV];
    float s = 0.f, q = 0.f;
    #pragma unroll
    for (int v = 0; v < VV; v++) {
        float xv = sF[c*FSTR + v] + btc;
        vals[v] = xv; s += xv; q += xv*xv;
    }
    blk_reduce2(s, q, red);
    float m = s * (1.f/6400.f);
    float var = q * (1.f/6400.f) - m*m;
    float rs = rsqrtf(var + 1e-5f);
    float pool = 0.f;
    #pragma unroll
    for (int v = 0; v < VV; v++) {
        float res = (t >= 4) ? HT[(size_t)((t-4)*32 + v)*CC + c] : 0.f;
        float o = fmaxf((vals[v]-m)*rs*lnw[c*VV+v] + lnb[c*VV+v] + res, 0.f);
        pool += o;
    }
    sp[c] = pool * (1.f/VV);
    __syncthreads();
    if (tid < NCC) {
        float acc = bout[tid];
        for (int cc = 0; cc < CC; cc++) acc = fmaf(Wout[tid*CC+cc], sp[cc], acc);
        out[t*NCC + tid] = acc;
    }
}

// ---------------- launch ----------------

extern "C" void kernel_launch(void* const* d_in, const int* in_sizes, int n_in,
                              void* d_out, int out_size, void* d_ws, size_t ws_size,
                              hipStream_t stream) {
    const float* x    = (const float*)d_in[0];
    const float* A    = (const float*)d_in[1];
    const float* lniw = (const float*)d_in[2];
    const float* lnib = (const float*)d_in[3];
    const float* Win  = (const float*)d_in[4];
    const float* bin  = (const float*)d_in[5];
    const float* Wg   = (const float*)d_in[6];
    const float* bg   = (const float*)d_in[7];
    const float* ln1w = (const float*)d_in[8];
    const float* ln1b = (const float*)d_in[9];
    const float* Wt   = (const float*)d_in[10];
    const float* bt   = (const float*)d_in[11];
    const float* ln2w = (const float*)d_in[12];
    const float* ln2b = (const float*)d_in[13];
    const float* imp  = (const float*)d_in[14];
    const float* Wout = (const float*)d_in[15];
    const float* bout = (const float*)d_in[16];
    float* out = (float*)d_out;

    float* ws = (float*)d_ws;
    size_t off = 0;
    auto alloc = [&](size_t n) { float* p = ws + off; off += (n + 255) & ~(size_t)255; return p; };
    float* H0   = alloc((size_t)N4*CC);
    float* H1   = alloc((size_t)N4*CC);
    float* TC   = alloc((size_t)CC*N4);
    float* bgAl = alloc((size_t)LL*CC*32);
    us16* Wgb  = (us16*)alloc((size_t)LL*KK*CC*CC/2);
    us16* Wt2b = (us16*)alloc((size_t)LL*CC*KDIM2/2);
    us16* Hbt2 = (us16*)alloc((size_t)N4*CC/2);
    us16* Ut2  = (us16*)alloc((size_t)UR*CC/2);
    us16* AlTb = (us16*)alloc((size_t)LL*KK*32*32/2);
    us16* Ybt  = (us16*)alloc((size_t)TT*CC*96/2);
    (void)ws_size; (void)in_sizes; (void)n_in; (void)out_size;

    k_prep<<<(PTOT + 255)/256, 256, 0, stream>>>(Wg, Wt, A, imp, bg,
                                                 Wgb, Wt2b, AlTb, bgAl);
    k_h0<<<TT, 256, 0, stream>>>(x, lniw, lnib, Win, bin, H0, Hbt2);

    float* hPrev = H0; float* hNext = H1;
    for (int l = 0; l < LL; l++) {
        if (l == 0) {
            k_gemm1<0><<<dim3(64, 12), 256, 0, stream>>>(
                Wgb, Hbt2, TC, hPrev, ln2w, ln2b, bt, hNext, Ybt);
        } else {
            k_gemm1<1><<<dim3(64, 12), 256, 0, stream>>>(
                Wgb + (size_t)l*KK*CC*CC, Hbt2, TC, hPrev,
                ln2w + (size_t)(l-1)*CC*VV, ln2b + (size_t)(l-1)*CC*VV,
                bt + (size_t)(l-1)*CC, hNext, Ybt);
            float* tmp = hPrev; hPrev = hNext; hNext = tmp;
        }
        k_adj<<<TT + 8, 256, 0, stream>>>(
            Ybt, AlTb + (size_t)l*KK*32*32, bgAl + (size_t)l*CC*32,
            ln1w + (size_t)l*CC*VV, ln1b + (size_t)l*CC*VV, Ut2);
        k_gemm2<<<dim3(N4/64, CC/64), 256, 0, stream>>>(
            Wt2b + (size_t)l*CC*KDIM2, Ut2, TC);
    }
    k_out<<<TT, 256, 0, stream>>>(TC, hPrev,
        bt + (size_t)(LL-1)*CC, ln2w + (size_t)(LL-1)*CC*VV, ln2b + (size_t)(LL-1)*CC*VV,
        Wout, bout, out);
}

// Round 8
// 816.242 us; speedup vs baseline: 5.4846x; 1.3821x over previous
//
#include <hip/hip_runtime.h>

#define TT  128
#define CC  256
#define VV  25
#define KK  3
#define GG  9
#define LL  9
#define NCC 60
#define CINN 3
#define TV    (TT*VV)          // 3200 (input x layout)
#define KDIM2 (CC*GG)          // 2304
#define UR    ((TT+8)*32)      // 4352 Ut2 rows: row = (t+8)*32+v
#define YSTR  104              // LDS Yt row stride (shorts)
#define HSTR  264              // LDS sH row stride (shorts), bank-skewed

typedef __attribute__((ext_vector_type(8))) short bf16x8;
typedef __attribute__((ext_vector_type(4))) float f32x4;
typedef unsigned short us16;

__device__ __forceinline__ us16 f2bf(float f) {
    union { float f; unsigned u; } a; a.f = f;
    unsigned r = a.u + 0x7fff + ((a.u >> 16) & 1);
    return (us16)(r >> 16);
}
__device__ __forceinline__ bf16x8 ld8(const us16* p) { return *(const bf16x8*)p; }

// ---------------- merged prep kernel ----------------

#define PN1 (LL*KK*CC*CC)
#define PN2 (LL*CC*CC*GG)
#define PN3 (LL*KK*32*32)
#define PN4 (LL*CC*32)
#define PTOT (PN1+PN2+PN3+PN4)

__global__ void k_prep(const float* __restrict__ Wg, const float* __restrict__ Wt,
                       const float* __restrict__ A, const float* __restrict__ imp,
                       const float* __restrict__ bg,
                       us16* __restrict__ Wgb, us16* __restrict__ Wt2b,
                       us16* __restrict__ AlTb, float* __restrict__ bgAl) {
    int i = blockIdx.x * 256 + threadIdx.x;
    if (i < PN1) {
        Wgb[i] = f2bf(Wg[i]);
    } else if (i < PN1 + PN2) {
        int j = i - PN1;
        int kk = j % (CC*GG);
        int o  = (j / (CC*GG)) % CC;
        int l  = j / (CC*CC*GG);
        int g = kk >> 8, c = kk & 255;
        Wt2b[j] = f2bf(Wt[((size_t)(l*CC + o)*CC + c)*GG + g]);
    } else if (i < PN1 + PN2 + PN3) {
        int j = i - PN1 - PN2;
        int v = j & 31, w = (j >> 5) & 31;
        int lk = j >> 10, k = lk % KK, l = lk / KK;
        float val = 0.f;
        if (v < VV && w < VV)
            val = A[(k*VV+v)*VV + w] * imp[((size_t)(l*KK+k)*VV+v)*VV + w];
        AlTb[j] = f2bf(val);
    } else if (i < PTOT) {
        int j = i - PN1 - PN2 - PN3;
        int w = j & 31, c = (j >> 5) & 255, l = j >> 13;
        float s = 0.f;
        if (w < VV) {
            for (int k = 0; k < KK; k++) {
                float col = 0.f;
                for (int v = 0; v < VV; v++)
                    col += A[(k*VV+v)*VV + w] * imp[((size_t)(l*KK+k)*VV+v)*VV + w];
                s += bg[l*KK*CC + k*CC + c] * col;
            }
        }
        bgAl[j] = s;
    }
}

// ---------------- block reduce (sum, sumsq) ----------------

__device__ __forceinline__ void blk_reduce2(float& s, float& q, float* red) {
    #pragma unroll
    for (int off = 32; off; off >>= 1) {
        s += __shfl_down(s, off);
        q += __shfl_down(q, off);
    }
    int lane = threadIdx.x & 63, w = threadIdx.x >> 6;
    if (lane == 0) { red[w] = s; red[4+w] = q; }
    __syncthreads();
    s = red[0]+red[1]+red[2]+red[3];
    q = red[4]+red[5]+red[6]+red[7];
}

// ---------------- fused gcn: [h0] -> Y=Wg@h (MFMA) -> adjacency (MFMA) -> LN1 -> Ut2 ----------------
// One block per frame (blocks 128..135 write the 8 history pad rows).
// FIRST=1: computes h0 = fcn_in(LN_in(x_t)) into LDS (no global round-trip),
// writes HT0 for the layer-0 residual; B-fragments come from LDS.

template<int FIRST>
__global__ __launch_bounds__(256) void k_gcn(
    const float* __restrict__ x, const float* __restrict__ lniw,
    const float* __restrict__ lnib, const float* __restrict__ Win,
    const float* __restrict__ bin,
    const us16* __restrict__ Wgb, const us16* __restrict__ Hbt2,
    const us16* __restrict__ AlTb, const float* __restrict__ bgAl,
    const float* __restrict__ lnw, const float* __restrict__ lnb,
    float* __restrict__ HT0, us16* __restrict__ Ut2) {

    const int t = blockIdx.x, tid = threadIdx.x;
    if (t >= TT) {                     // 8 history pad frames: relu(ln1_b)
        int tp = t - TT, c = tid;
        #pragma unroll
        for (int w = 0; w < 32; w++) {
            float u = (w < VV) ? fmaxf(lnb[c*VV + w], 0.f) : 0.f;
            Ut2[(size_t)(tp*32 + w)*CC + c] = f2bf(u);
        }
        return;
    }
    __shared__ us16 Yt[CC*YSTR];                 // 53.2 KB
    __shared__ us16 sH[FIRST ? 32*HSTR : 4];     // 16.9 KB (FIRST only)
    __shared__ float red[8];
    __shared__ float sx[80];
    __shared__ float sh[80];
    const int wave = tid >> 6, lane = tid & 63, quad = lane >> 4, l16 = lane & 15;

    if (FIRST) {
        // ---- h0 = W_in @ LN_in(x_t) + b_in ----
        if (tid < CINN*VV)
            sx[tid] = x[(size_t)(tid/VV)*TV + t*VV + (tid%VV)];
        __syncthreads();
        float s = 0.f, q = 0.f;
        for (int i = 0; i < CINN*VV; i++) { float v = sx[i]; s += v; q += v*v; }
        float m  = s * (1.f/75.f);
        float var = q * (1.f/75.f) - m*m;
        float rs = rsqrtf(var + 1e-5f);
        if (tid < CINN*VV)
            sh[tid] = (sx[tid]-m)*rs*lniw[tid] + lnib[tid];
        __syncthreads();
        int c = tid;
        float w0 = Win[c*3+0], w1 = Win[c*3+1], w2 = Win[c*3+2], bb = bin[c];
        #pragma unroll
        for (int v = 0; v < VV; v++) {
            float acc = bb + w0*sh[v] + w1*sh[VV+v] + w2*sh[2*VV+v];
            HT0[(size_t)(t*32 + v)*CC + c] = acc;
            sH[v*HSTR + c] = f2bf(acc);
        }
        #pragma unroll
        for (int v = VV; v < 32; v++)
            sH[v*HSTR + c] = 0;
        __syncthreads();
    }

    // ---- phase 1: Y = Wg @ h  (M=768, N=32, K=256), B register-cached ----
    bf16x8 bf[2][8];
    #pragma unroll
    for (int nt = 0; nt < 2; nt++)
        #pragma unroll
        for (int s = 0; s < 8; s++) {
            if (FIRST)
                bf[nt][s] = *(const bf16x8*)(sH + (nt*16 + l16)*HSTR + s*32 + quad*8);
            else
                bf[nt][s] = ld8(Hbt2 + (size_t)(t*32 + nt*16 + l16)*CC + s*32 + quad*8);
        }
    f32x4 acc[12][2];
    #pragma unroll
    for (int mt = 0; mt < 12; mt++) { acc[mt][0] = (f32x4){}; acc[mt][1] = (f32x4){}; }
    #pragma unroll
    for (int mt = 0; mt < 12; mt++) {
        const us16* ap = Wgb + (size_t)(wave*192 + mt*16 + l16)*CC + quad*8;
        #pragma unroll
        for (int s = 0; s < 8; s++) {
            bf16x8 a = ld8(ap + s*32);
            acc[mt][0] = __builtin_amdgcn_mfma_f32_16x16x32_bf16(a, bf[0][s], acc[mt][0], 0,0,0);
            acc[mt][1] = __builtin_amdgcn_mfma_f32_16x16x32_bf16(a, bf[1][s], acc[mt][1], 0,0,0);
        }
    }
    #pragma unroll
    for (int mt = 0; mt < 12; mt++)
        #pragma unroll
        for (int nt = 0; nt < 2; nt++)
            #pragma unroll
            for (int r = 0; r < 4; r++) {
                int m = wave*192 + mt*16 + quad*4 + r;
                Yt[(m & 255)*YSTR + (m >> 8)*32 + nt*16 + l16] = f2bf(acc[mt][nt][r]);
            }
    __syncthreads();

    // ---- phase 2: Z[c][w] = sum_{k,v} Yt[c][k*32+v] * Al[k][v][w] ----
    bf16x8 al[2][3];
    #pragma unroll
    for (int nt = 0; nt < 2; nt++)
        #pragma unroll
        for (int s = 0; s < 3; s++)
            al[nt][s] = ld8(AlTb + (size_t)(s*32 + nt*16 + l16)*32 + quad*8);
    f32x4 z[4][2];
    #pragma unroll
    for (int mt = 0; mt < 4; mt++) { z[mt][0] = (f32x4){}; z[mt][1] = (f32x4){}; }
    #pragma unroll
    for (int mt = 0; mt < 4; mt++)
        #pragma unroll
        for (int s = 0; s < 3; s++) {
            bf16x8 a = *(const bf16x8*)(Yt + (wave*64 + mt*16 + l16)*YSTR + s*32 + quad*8);
            z[mt][0] = __builtin_amdgcn_mfma_f32_16x16x32_bf16(a, al[0][s], z[mt][0], 0,0,0);
            z[mt][1] = __builtin_amdgcn_mfma_f32_16x16x32_bf16(a, al[1][s], z[mt][1], 0,0,0);
        }

    // ---- bias fold + LN1 + ReLU -> Ut2 ----
    float s_ = 0.f, q_ = 0.f;
    #pragma unroll
    for (int mt = 0; mt < 4; mt++)
        #pragma unroll
        for (int nt = 0; nt < 2; nt++)
            #pragma unroll
            for (int r = 0; r < 4; r++) {
                int c = wave*64 + mt*16 + quad*4 + r;
                int w = nt*16 + l16;
                float zb = z[mt][nt][r] + bgAl[c*32 + w];
                z[mt][nt][r] = zb;
                if (w < VV) { s_ += zb; q_ += zb*zb; }
            }
    blk_reduce2(s_, q_, red);
    float m = s_ * (1.f/6400.f);
    float var = q_ * (1.f/6400.f) - m*m;
    float rs = rsqrtf(var + 1e-5f);
    #pragma unroll
    for (int mt = 0; mt < 4; mt++)
        #pragma unroll
        for (int nt = 0; nt < 2; nt++) {
            int w = nt*16 + l16;
            if (w < VV) {
                int c0 = wave*64 + mt*16 + quad*4;
                ushort4 pk;
                float u0 = fmaxf((z[mt][nt][0]-m)*rs*lnw[(c0+0)*VV+w] + lnb[(c0+0)*VV+w], 0.f);
                float u1 = fmaxf((z[mt][nt][1]-m)*rs*lnw[(c0+1)*VV+w] + lnb[(c0+1)*VV+w], 0.f);
                float u2 = fmaxf((z[mt][nt][2]-m)*rs*lnw[(c0+2)*VV+w] + lnb[(c0+2)*VV+w], 0.f);
                float u3 = fmaxf((z[mt][nt][3]-m)*rs*lnw[(c0+3)*VV+w] + lnb[(c0+3)*VV+w], 0.f);
                pk.x = f2bf(u0); pk.y = f2bf(u1); pk.z = f2bf(u2); pk.w = f2bf(u3);
                *(ushort4*)(Ut2 + (size_t)((t+8)*32 + w)*CC + c0) = pk;
            }
        }
    #pragma unroll
    for (int r = VV; r < 32; r++)
        Ut2[(size_t)((t+8)*32 + r)*CC + tid] = 0;
}

// ---------------- fused tcn: GEMM2 (depth-3 pipeline) + bias + LN2 + residual + ReLU ----------------
// One block per frame. LAST=1: pool + classifier instead of H writes.

template<int LAST>
__global__ __launch_bounds__(256) void k_tcn(
    const us16* __restrict__ Wt2, const us16* __restrict__ Ut2,
    const float* __restrict__ btv,
    const float* __restrict__ lnw, const float* __restrict__ lnb,
    const float* __restrict__ HprevT, float* __restrict__ HnextT,
    us16* __restrict__ Hbt2,
    const float* __restrict__ Wout, const float* __restrict__ bout,
    float* __restrict__ out) {

    const int t = blockIdx.x, tid = threadIdx.x;
    const int wave = tid >> 6, lane = tid & 63, quad = lane >> 4, l16 = lane & 15;
    __shared__ float red[8];
    __shared__ float so[LAST ? CC*33 : 4];

    f32x4 acc[4][2];
    #pragma unroll
    for (int mt = 0; mt < 4; mt++) { acc[mt][0] = (f32x4){}; acc[mt][1] = (f32x4){}; }

    bf16x8 sa[3][4], sb[3][2];
    const us16* apb = Wt2 + (size_t)(wave*64 + l16)*KDIM2 + quad*8;

    #define LOADSTAGE(st, it) { \
        int k0 = (it)*32; \
        int g = k0 >> 8; \
        const us16* ub = Ut2 + (size_t)((t + 8 - g)*32)*CC + (k0 & 255) + quad*8; \
        sb[st][0] = ld8(ub + (size_t)l16*CC); \
        sb[st][1] = ld8(ub + (size_t)(16 + l16)*CC); \
        _Pragma("unroll") \
        for (int mt = 0; mt < 4; mt++) \
            sa[st][mt] = ld8(apb + (size_t)(mt*16)*KDIM2 + k0); \
    }
    #define MFSTAGE(st) { \
        _Pragma("unroll") \
        for (int mt = 0; mt < 4; mt++) { \
            acc[mt][0] = __builtin_amdgcn_mfma_f32_16x16x32_bf16(sa[st][mt], sb[st][0], acc[mt][0], 0,0,0); \
            acc[mt][1] = __builtin_amdgcn_mfma_f32_16x16x32_bf16(sa[st][mt], sb[st][1], acc[mt][1], 0,0,0); \
        } \
    }

    LOADSTAGE(0, 0); LOADSTAGE(1, 1); LOADSTAGE(2, 2);
    #pragma unroll 3
    for (int it = 3; it < KDIM2/32; it++) {
        int st = it % 3;
        switch (st) {
            case 0: MFSTAGE(0); LOADSTAGE(0, it); break;
            case 1: MFSTAGE(1); LOADSTAGE(1, it); break;
            default: MFSTAGE(2); LOADSTAGE(2, it); break;
        }
    }
    MFSTAGE(0); MFSTAGE(1); MFSTAGE(2);

    // ---- bias + LN2 stats ----
    float s_ = 0.f, q_ = 0.f;
    #pragma unroll
    for (int mt = 0; mt < 4; mt++)
        #pragma unroll
        for (int nt = 0; nt < 2; nt++)
            #pragma unroll
            for (int r = 0; r < 4; r++) {
                int c = wave*64 + mt*16 + quad*4 + r;
                int v = nt*16 + l16;
                float val = acc[mt][nt][r] + btv[c];
                acc[mt][nt][r] = val;
                if (v < VV) { s_ += val; q_ += val*val; }
            }
    blk_reduce2(s_, q_, red);
    float m = s_ * (1.f/6400.f);
    float var = q_ * (1.f/6400.f) - m*m;
    float rs = rsqrtf(var + 1e-5f);

    #pragma unroll
    for (int mt = 0; mt < 4; mt++)
        #pragma unroll
        for (int nt = 0; nt < 2; nt++) {
            int v = nt*16 + l16;
            if (v < VV) {
                int c0 = wave*64 + mt*16 + quad*4;
                float o[4];
                #pragma unroll
                for (int r = 0; r < 4; r++) {
                    int c = c0 + r;
                    float res = (t >= 4) ? HprevT[(size_t)((t-4)*32 + v)*CC + c] : 0.f;
                    o[r] = fmaxf((acc[mt][nt][r]-m)*rs*lnw[c*VV+v] + lnb[c*VV+v] + res, 0.f);
                }
                if (LAST) {
                    #pragma unroll
                    for (int r = 0; r < 4; r++) so[(c0+r)*33 + v] = o[r];
                } else {
                    float4 fv; fv.x = o[0]; fv.y = o[1]; fv.z = o[2]; fv.w = o[3];
                    *(float4*)(HnextT + (size_t)(t*32 + v)*CC + c0) = fv;
                    ushort4 pk;
                    pk.x = f2bf(o[0]); pk.y = f2bf(o[1]); pk.z = f2bf(o[2]); pk.w = f2bf(o[3]);
                    *(ushort4*)(Hbt2 + (size_t)(t*32 + v)*CC + c0) = pk;
                }
            }
        }
    if (LAST) {
        __syncthreads();
        int c = tid;
        float pool = 0.f;
        #pragma unroll
        for (int v = 0; v < VV; v++) pool += so[c*33 + v];
        so[c*33 + 32] = pool * (1.f/VV);
        __syncthreads();
        if (tid < NCC) {
            float a = bout[tid];
            for (int cc = 0; cc < CC; cc++) a = fmaf(Wout[tid*CC+cc], so[cc*33 + 32], a);
            out[t*NCC + tid] = a;
        }
    } else {
        #pragma unroll
        for (int v = VV; v < 32; v++)
            Hbt2[(size_t)(t*32 + v)*CC + tid] = 0;
    }
}

// ---------------- launch ----------------

extern "C" void kernel_launch(void* const* d_in, const int* in_sizes, int n_in,
                              void* d_out, int out_size, void* d_ws, size_t ws_size,
                              hipStream_t stream) {
    const float* x    = (const float*)d_in[0];
    const float* A    = (const float*)d_in[1];
    const float* lniw = (const float*)d_in[2];
    const float* lnib = (const float*)d_in[3];
    const float* Win  = (const float*)d_in[4];
    const float* bin  = (const float*)d_in[5];
    const float* Wg   = (const float*)d_in[6];
    const float* bg   = (const float*)d_in[7];
    const float* ln1w = (const float*)d_in[8];
    const float* ln1b = (const float*)d_in[9];
    const float* Wt   = (const float*)d_in[10];
    const float* bt   = (const float*)d_in[11];
    const float* ln2w = (const float*)d_in[12];
    const float* ln2b = (const float*)d_in[13];
    const float* imp  = (const float*)d_in[14];
    const float* Wout = (const float*)d_in[15];
    const float* bout = (const float*)d_in[16];
    float* out = (float*)d_out;

    float* ws = (float*)d_ws;
    size_t off = 0;
    auto alloc = [&](size_t n) { float* p = ws + off; off += (n + 255) & ~(size_t)255; return p; };
    float* HT0  = alloc((size_t)TT*32*CC);
    float* HT1  = alloc((size_t)TT*32*CC);
    float* bgAl = alloc((size_t)LL*CC*32);
    us16* Wgb  = (us16*)alloc((size_t)LL*KK*CC*CC/2);
    us16* Wt2b = (us16*)alloc((size_t)LL*CC*KDIM2/2);
    us16* Hbt2 = (us16*)alloc((size_t)TT*32*CC/2);
    us16* Ut2  = (us16*)alloc((size_t)UR*CC/2);
    us16* AlTb = (us16*)alloc((size_t)LL*KK*32*32/2);
    (void)ws_size; (void)in_sizes; (void)n_in; (void)out_size;

    k_prep<<<(PTOT + 255)/256, 256, 0, stream>>>(Wg, Wt, A, imp, bg,
                                                 Wgb, Wt2b, AlTb, bgAl);

    float* hPrev = HT0; float* hNext = HT1;
    for (int l = 0; l < LL; l++) {
        if (l == 0)
            k_gcn<1><<<TT + 8, 256, 0, stream>>>(
                x, lniw, lnib, Win, bin,
                Wgb, Hbt2, AlTb, bgAl, ln1w, ln1b, HT0, Ut2);
        else
            k_gcn<0><<<TT + 8, 256, 0, stream>>>(
                x, lniw, lnib, Win, bin,
                Wgb + (size_t)l*KK*CC*CC, Hbt2,
                AlTb + (size_t)l*KK*32*32, bgAl + (size_t)l*CC*32,
                ln1w + (size_t)l*CC*VV, ln1b + (size_t)l*CC*VV, HT0, Ut2);
        if (l < LL-1) {
            k_tcn<0><<<TT, 256, 0, stream>>>(
                Wt2b + (size_t)l*CC*KDIM2, Ut2, bt + (size_t)l*CC,
                ln2w + (size_t)l*CC*VV, ln2b + (size_t)l*CC*VV,
                hPrev, hNext, Hbt2, Wout, bout, out);
            float* tmp = hPrev; hPrev = hNext; hNext = tmp;
        } else {
            k_tcn<1><<<TT, 256, 0, stream>>>(
                Wt2b + (size_t)l*CC*KDIM2, Ut2, bt + (size_t)l*CC,
                ln2w + (size_t)l*CC*VV, ln2b + (size_t)l*CC*VV,
                hPrev, hNext, Hbt2, Wout, bout, out);
        }
    }
}

// Round 9
// 785.758 us; speedup vs baseline: 5.6974x; 1.0388x over previous
//
#include <hip/hip_runtime.h>

#define TT  128
#define CC  256
#define VV  25
#define KK  3
#define GG  9
#define LL  9
#define NCC 60
#define CINN 3
#define TV    (TT*VV)          // 3200 (input x layout)
#define N4    4096             // TC columns: n = t*32+v
#define KDIM2 (CC*GG)          // 2304
#define UR    ((TT+8)*32)      // 4352 Ut2 rows: row = (t+8)*32+v
#define YSTR  104              // LDS Yt row stride (shorts)
#define HSTR  264              // LDS sH row stride (shorts), bank-skewed
#define FSTR  33               // LDS fp32 stage row stride

typedef __attribute__((ext_vector_type(8))) short bf16x8;
typedef __attribute__((ext_vector_type(4))) float f32x4;
typedef unsigned short us16;

__device__ __forceinline__ us16 f2bf(float f) {
    union { float f; unsigned u; } a; a.f = f;
    unsigned r = a.u + 0x7fff + ((a.u >> 16) & 1);
    return (us16)(r >> 16);
}
__device__ __forceinline__ bf16x8 ld8(const us16* p) { return *(const bf16x8*)p; }

// ---------------- merged prep kernel ----------------

#define PN1 (LL*KK*CC*CC)
#define PN2 (LL*CC*CC*GG)
#define PN3 (LL*KK*32*32)
#define PN4 (LL*CC*32)
#define PTOT (PN1+PN2+PN3+PN4)

__global__ void k_prep(const float* __restrict__ Wg, const float* __restrict__ Wt,
                       const float* __restrict__ A, const float* __restrict__ imp,
                       const float* __restrict__ bg,
                       us16* __restrict__ Wgb, us16* __restrict__ Wt2b,
                       us16* __restrict__ AlTb, float* __restrict__ bgAl) {
    int i = blockIdx.x * 256 + threadIdx.x;
    if (i < PN1) {
        Wgb[i] = f2bf(Wg[i]);
    } else if (i < PN1 + PN2) {
        int j = i - PN1;
        int kk = j % (CC*GG);
        int o  = (j / (CC*GG)) % CC;
        int l  = j / (CC*CC*GG);
        int g = kk >> 8, c = kk & 255;
        Wt2b[j] = f2bf(Wt[((size_t)(l*CC + o)*CC + c)*GG + g]);
    } else if (i < PN1 + PN2 + PN3) {
        int j = i - PN1 - PN2;
        int v = j & 31, w = (j >> 5) & 31;
        int lk = j >> 10, k = lk % KK, l = lk / KK;
        float val = 0.f;
        if (v < VV && w < VV)
            val = A[(k*VV+v)*VV + w] * imp[((size_t)(l*KK+k)*VV+v)*VV + w];
        AlTb[j] = f2bf(val);
    } else if (i < PTOT) {
        int j = i - PN1 - PN2 - PN3;
        int w = j & 31, c = (j >> 5) & 255, l = j >> 13;
        float s = 0.f;
        if (w < VV) {
            for (int k = 0; k < KK; k++) {
                float col = 0.f;
                for (int v = 0; v < VV; v++)
                    col += A[(k*VV+v)*VV + w] * imp[((size_t)(l*KK+k)*VV+v)*VV + w];
                s += bg[l*KK*CC + k*CC + c] * col;
            }
        }
        bgAl[j] = s;
    }
}

// ---------------- block reduce (sum, sumsq) ----------------

__device__ __forceinline__ void blk_reduce2(float& s, float& q, float* red) {
    #pragma unroll
    for (int off = 32; off; off >>= 1) {
        s += __shfl_down(s, off);
        q += __shfl_down(q, off);
    }
    int lane = threadIdx.x & 63, w = threadIdx.x >> 6;
    if (lane == 0) { red[w] = s; red[4+w] = q; }
    __syncthreads();
    s = red[0]+red[1]+red[2]+red[3];
    q = red[4]+red[5]+red[6]+red[7];
}

// ---------------- fused gcn ----------------
// One block per frame (blocks 128..135 write the 8 history pad rows).
// FIRST=1: prologue computes h^0 = fcn_in(LN_in(x_t)).
// FIRST=0: prologue computes h^l = relu(LN2(TC+bt) + HresidT(t-4)) from the
//          previous layer's GEMM2 output (zero redundancy: 1 block = 1 frame).
// Prologue result -> sH (LDS, B-operand layout) + HT (fp32, next residual).
// Then: Y = Wg@h (MFMA, B register-cached) -> adjacency (MFMA) -> LN1 -> Ut2.

template<int FIRST>
__global__ __launch_bounds__(256) void k_gcn(
    const float* __restrict__ x, const float* __restrict__ lniw,
    const float* __restrict__ lnib, const float* __restrict__ Win,
    const float* __restrict__ bin,
    const float* __restrict__ TC, const float* __restrict__ btv,
    const float* __restrict__ ln2w, const float* __restrict__ ln2b,
    const float* __restrict__ HresidT,
    const us16* __restrict__ Wgb,
    const us16* __restrict__ AlTb, const float* __restrict__ bgAl,
    const float* __restrict__ lnw, const float* __restrict__ lnb,
    float* __restrict__ HT, us16* __restrict__ Ut2) {

    const int t = blockIdx.x, tid = threadIdx.x;
    if (t >= TT) {                     // 8 history pad frames: relu(ln1_b)
        int tp = t - TT, c = tid;
        #pragma unroll
        for (int w = 0; w < 32; w++) {
            float u = (w < VV) ? fmaxf(lnb[c*VV + w], 0.f) : 0.f;
            Ut2[(size_t)(tp*32 + w)*CC + c] = f2bf(u);
        }
        return;
    }
    __shared__ __align__(16) us16 pool[CC*YSTR];   // Yt (53.2KB) / sF (33.8KB) overlay
    __shared__ __align__(16) us16 sH[32*HSTR];     // 16.9 KB
    __shared__ float red[8];
    __shared__ float sx[80];
    __shared__ float sh[80];
    const int wave = tid >> 6, lane = tid & 63, quad = lane >> 4, l16 = lane & 15;

    if (FIRST) {
        // ---- h^0 = W_in @ LN_in(x_t) + b_in ----
        if (tid < CINN*VV)
            sx[tid] = x[(size_t)(tid/VV)*TV + t*VV + (tid%VV)];
        __syncthreads();
        float s = 0.f, q = 0.f;
        for (int i = 0; i < CINN*VV; i++) { float v = sx[i]; s += v; q += v*v; }
        float m  = s * (1.f/75.f);
        float var = q * (1.f/75.f) - m*m;
        float rs = rsqrtf(var + 1e-5f);
        if (tid < CINN*VV)
            sh[tid] = (sx[tid]-m)*rs*lniw[tid] + lnib[tid];
        __syncthreads();
        int c = tid;
        float w0 = Win[c*3+0], w1 = Win[c*3+1], w2 = Win[c*3+2], bb = bin[c];
        #pragma unroll
        for (int v = 0; v < VV; v++) {
            float acc = bb + w0*sh[v] + w1*sh[VV+v] + w2*sh[2*VV+v];
            HT[(size_t)(t*32 + v)*CC + c] = acc;
            sH[v*HSTR + c] = f2bf(acc);
        }
        #pragma unroll
        for (int v = VV; v < 32; v++)
            sH[v*HSTR + c] = 0;
        __syncthreads();
    } else {
        // ---- h^l = relu(LN2(TC + bt) + resid) ----
        float* sF = (float*)pool;
        #pragma unroll
        for (int j = 0; j < 8; j++) {
            int cs = j*32 + (tid >> 3);
            int v4 = (tid & 7) * 4;
            float4 xv = *(const float4*)(TC + (size_t)cs*N4 + t*32 + v4);
            sF[cs*FSTR + v4+0] = xv.x; sF[cs*FSTR + v4+1] = xv.y;
            sF[cs*FSTR + v4+2] = xv.z; sF[cs*FSTR + v4+3] = xv.w;
        }
        __syncthreads();
        int c = tid;
        float btc = btv[c];
        float vals[VV];
        float s = 0.f, q = 0.f;
        #pragma unroll
        for (int v = 0; v < VV; v++) {
            float xv = sF[c*FSTR + v] + btc;
            vals[v] = xv; s += xv; q += xv*xv;
        }
        blk_reduce2(s, q, red);
        float m = s * (1.f/6400.f);
        float var = q * (1.f/6400.f) - m*m;
        float rs = rsqrtf(var + 1e-5f);
        #pragma unroll
        for (int v = 0; v < VV; v++) {
            float res = (t >= 4) ? HresidT[(size_t)((t-4)*32 + v)*CC + c] : 0.f;
            float o = fmaxf((vals[v]-m)*rs*ln2w[c*VV+v] + ln2b[c*VV+v] + res, 0.f);
            HT[(size_t)(t*32 + v)*CC + c] = o;
            sH[v*HSTR + c] = f2bf(o);
        }
        #pragma unroll
        for (int v = VV; v < 32; v++)
            sH[v*HSTR + c] = 0;
        __syncthreads();
    }

    // ---- phase 1: Y = Wg @ h  (M=768, N=32, K=256), B register-cached from sH ----
    us16* Yt = pool;
    bf16x8 bf[2][8];
    #pragma unroll
    for (int nt = 0; nt < 2; nt++)
        #pragma unroll
        for (int s = 0; s < 8; s++)
            bf[nt][s] = *(const bf16x8*)(sH + (nt*16 + l16)*HSTR + s*32 + quad*8);
    f32x4 acc[12][2];
    #pragma unroll
    for (int mt = 0; mt < 12; mt++) { acc[mt][0] = (f32x4){}; acc[mt][1] = (f32x4){}; }
    #pragma unroll
    for (int mt = 0; mt < 12; mt++) {
        const us16* ap = Wgb + (size_t)(wave*192 + mt*16 + l16)*CC + quad*8;
        #pragma unroll
        for (int s = 0; s < 8; s++) {
            bf16x8 a = ld8(ap + s*32);
            acc[mt][0] = __builtin_amdgcn_mfma_f32_16x16x32_bf16(a, bf[0][s], acc[mt][0], 0,0,0);
            acc[mt][1] = __builtin_amdgcn_mfma_f32_16x16x32_bf16(a, bf[1][s], acc[mt][1], 0,0,0);
        }
    }
    __syncthreads();   // pool: sF -> Yt reuse
    #pragma unroll
    for (int mt = 0; mt < 12; mt++)
        #pragma unroll
        for (int nt = 0; nt < 2; nt++)
            #pragma unroll
            for (int r = 0; r < 4; r++) {
                int m = wave*192 + mt*16 + quad*4 + r;
                Yt[(m & 255)*YSTR + (m >> 8)*32 + nt*16 + l16] = f2bf(acc[mt][nt][r]);
            }
    __syncthreads();

    // ---- phase 2: Z[c][w] = sum_{k,v} Yt[c][k*32+v] * Al[k][v][w] ----
    bf16x8 al[2][3];
    #pragma unroll
    for (int nt = 0; nt < 2; nt++)
        #pragma unroll
        for (int s = 0; s < 3; s++)
            al[nt][s] = ld8(AlTb + (size_t)(s*32 + nt*16 + l16)*32 + quad*8);
    f32x4 z[4][2];
    #pragma unroll
    for (int mt = 0; mt < 4; mt++) { z[mt][0] = (f32x4){}; z[mt][1] = (f32x4){}; }
    #pragma unroll
    for (int mt = 0; mt < 4; mt++)
        #pragma unroll
        for (int s = 0; s < 3; s++) {
            bf16x8 a = *(const bf16x8*)(Yt + (wave*64 + mt*16 + l16)*YSTR + s*32 + quad*8);
            z[mt][0] = __builtin_amdgcn_mfma_f32_16x16x32_bf16(a, al[0][s], z[mt][0], 0,0,0);
            z[mt][1] = __builtin_amdgcn_mfma_f32_16x16x32_bf16(a, al[1][s], z[mt][1], 0,0,0);
        }

    // ---- bias fold + LN1 + ReLU -> Ut2 ----
    float s_ = 0.f, q_ = 0.f;
    #pragma unroll
    for (int mt = 0; mt < 4; mt++)
        #pragma unroll
        for (int nt = 0; nt < 2; nt++)
            #pragma unroll
            for (int r = 0; r < 4; r++) {
                int c = wave*64 + mt*16 + quad*4 + r;
                int w = nt*16 + l16;
                float zb = z[mt][nt][r] + bgAl[c*32 + w];
                z[mt][nt][r] = zb;
                if (w < VV) { s_ += zb; q_ += zb*zb; }
            }
    blk_reduce2(s_, q_, red);
    float m = s_ * (1.f/6400.f);
    float var = q_ * (1.f/6400.f) - m*m;
    float rs = rsqrtf(var + 1e-5f);
    #pragma unroll
    for (int mt = 0; mt < 4; mt++)
        #pragma unroll
        for (int nt = 0; nt < 2; nt++) {
            int w = nt*16 + l16;
            if (w < VV) {
                int c0 = wave*64 + mt*16 + quad*4;
                ushort4 pk;
                float u0 = fmaxf((z[mt][nt][0]-m)*rs*lnw[(c0+0)*VV+w] + lnb[(c0+0)*VV+w], 0.f);
                float u1 = fmaxf((z[mt][nt][1]-m)*rs*lnw[(c0+1)*VV+w] + lnb[(c0+1)*VV+w], 0.f);
                float u2 = fmaxf((z[mt][nt][2]-m)*rs*lnw[(c0+2)*VV+w] + lnb[(c0+2)*VV+w], 0.f);
                float u3 = fmaxf((z[mt][nt][3]-m)*rs*lnw[(c0+3)*VV+w] + lnb[(c0+3)*VV+w], 0.f);
                pk.x = f2bf(u0); pk.y = f2bf(u1); pk.z = f2bf(u2); pk.w = f2bf(u3);
                *(ushort4*)(Ut2 + (size_t)((t+8)*32 + w)*CC + c0) = pk;
            }
        }
    #pragma unroll
    for (int r = VV; r < 32; r++)
        Ut2[(size_t)((t+8)*32 + r)*CC + tid] = 0;
}

// ---------------- GEMM2: TC = Wt2 @ Ushift (256x4096, K=2304), depth-2 pipeline ----------------

__global__ __launch_bounds__(256) void k_gemm2(const us16* __restrict__ A,
                                               const us16* __restrict__ Ut2,
                                               float* __restrict__ TC) {
    const int tid = threadIdx.x;
    const int wave = tid >> 6, lane = tid & 63, quad = lane >> 4, l16 = lane & 15;
    const int m0w = blockIdx.y * 64 + (wave & 1) * 32;
    const int n0w = blockIdx.x * 64 + (wave >> 1) * 32;
    const us16* ap = A + (size_t)(m0w + l16) * KDIM2 + quad * 8;
    f32x4 acc00 = {}, acc01 = {}, acc10 = {}, acc11 = {};
    bf16x8 a0[2], a1[2], b0[2], b1[2];

    auto loadAB = [&](int k0, bf16x8& x0, bf16x8& x1, bf16x8& y0, bf16x8& y1) {
        x0 = ld8(ap + k0);
        x1 = ld8(ap + k0 + 16*KDIM2);
        int g = k0 >> 8;
        const us16* bp = Ut2 + (size_t)(n0w + (8-g)*32 + l16)*CC + (k0 & 255) + quad*8;
        y0 = ld8(bp);
        y1 = ld8(bp + 16*CC);
    };
    auto domfma = [&](bf16x8 x0, bf16x8 x1, bf16x8 y0, bf16x8 y1) {
        acc00 = __builtin_amdgcn_mfma_f32_16x16x32_bf16(x0, y0, acc00, 0,0,0);
        acc01 = __builtin_amdgcn_mfma_f32_16x16x32_bf16(x0, y1, acc01, 0,0,0);
        acc10 = __builtin_amdgcn_mfma_f32_16x16x32_bf16(x1, y0, acc10, 0,0,0);
        acc11 = __builtin_amdgcn_mfma_f32_16x16x32_bf16(x1, y1, acc11, 0,0,0);
    };

    loadAB(0,  a0[0], a1[0], b0[0], b1[0]);
    loadAB(32, a0[1], a1[1], b0[1], b1[1]);
    #pragma unroll 2
    for (int k0 = 64; k0 < KDIM2; k0 += 32) {
        int sl = (k0 >> 5) & 1;
        bf16x8 ta0 = a0[sl], ta1 = a1[sl], tb0 = b0[sl], tb1 = b1[sl];
        loadAB(k0, a0[sl], a1[sl], b0[sl], b1[sl]);
        domfma(ta0, ta1, tb0, tb1);
    }
    domfma(a0[0], a1[0], b0[0], b1[0]);
    domfma(a0[1], a1[1], b0[1], b1[1]);

    const int r0 = m0w + quad*4;
    const int col = n0w + l16;
    #pragma unroll
    for (int r = 0; r < 4; r++) {
        TC[(size_t)(r0 + r)*N4 + col]           = acc00[r];
        TC[(size_t)(r0 + r)*N4 + col + 16]      = acc01[r];
        TC[(size_t)(r0 + 16 + r)*N4 + col]      = acc10[r];
        TC[(size_t)(r0 + 16 + r)*N4 + col + 16] = acc11[r];
    }
}

// ---------------- final: LN2 + residual + ReLU + pool + classifier ----------------

__global__ __launch_bounds__(256) void k_fin(const float* __restrict__ TC,
                                             const float* __restrict__ HresidT,
                                             const float* __restrict__ btv,
                                             const float* __restrict__ lnw,
                                             const float* __restrict__ lnb,
                                             const float* __restrict__ Wout,
                                             const float* __restrict__ bout,
                                             float* __restrict__ out) {
    int t = blockIdx.x, tid = threadIdx.x;
    __shared__ float sF[CC*FSTR];
    __shared__ float red[8];
    __shared__ float sp[CC];
    #pragma unroll
    for (int j = 0; j < 8; j++) {
        int cs = j*32 + (tid >> 3);
        int v4 = (tid & 7) * 4;
        float4 xv = *(const float4*)(TC + (size_t)cs*N4 + t*32 + v4);
        sF[cs*FSTR + v4+0] = xv.x; sF[cs*FSTR + v4+1] = xv.y;
        sF[cs*FSTR + v4+2] = xv.z; sF[cs*FSTR + v4+3] = xv.w;
    }
    __syncthreads();
    int c = tid;
    float btc = btv[c];
    float vals[VV];
    float s = 0.f, q = 0.f;
    #pragma unroll
    for (int v = 0; v < VV; v++) {
        float xv = sF[c*FSTR + v] + btc;
        vals[v] = xv; s += xv; q += xv*xv;
    }
    blk_reduce2(s, q, red);
    float m = s * (1.f/6400.f);
    float var = q * (1.f/6400.f) - m*m;
    float rs = rsqrtf(var + 1e-5f);
    float pl = 0.f;
    #pragma unroll
    for (int v = 0; v < VV; v++) {
        float res = (t >= 4) ? HresidT[(size_t)((t-4)*32 + v)*CC + c] : 0.f;
        float o = fmaxf((vals[v]-m)*rs*lnw[c*VV+v] + lnb[c*VV+v] + res, 0.f);
        pl += o;
    }
    sp[c] = pl * (1.f/VV);
    __syncthreads();
    if (tid < NCC) {
        float a = bout[tid];
        for (int cc = 0; cc < CC; cc++) a = fmaf(Wout[tid*CC+cc], sp[cc], a);
        out[t*NCC + tid] = a;
    }
}

// ---------------- launch ----------------

extern "C" void kernel_launch(void* const* d_in, const int* in_sizes, int n_in,
                              void* d_out, int out_size, void* d_ws, size_t ws_size,
                              hipStream_t stream) {
    const float* x    = (const float*)d_in[0];
    const float* A    = (const float*)d_in[1];
    const float* lniw = (const float*)d_in[2];
    const float* lnib = (const float*)d_in[3];
    const float* Win  = (const float*)d_in[4];
    const float* bin  = (const float*)d_in[5];
    const float* Wg   = (const float*)d_in[6];
    const float* bg   = (const float*)d_in[7];
    const float* ln1w = (const float*)d_in[8];
    const float* ln1b = (const float*)d_in[9];
    const float* Wt   = (const float*)d_in[10];
    const float* bt   = (const float*)d_in[11];
    const float* ln2w = (const float*)d_in[12];
    const float* ln2b = (const float*)d_in[13];
    const float* imp  = (const float*)d_in[14];
    const float* Wout = (const float*)d_in[15];
    const float* bout = (const float*)d_in[16];
    float* out = (float*)d_out;

    float* ws = (float*)d_ws;
    size_t off = 0;
    auto alloc = [&](size_t n) { float* p = ws + off; off += (n + 255) & ~(size_t)255; return p; };
    float* HT0  = alloc((size_t)TT*32*CC);
    float* HT1  = alloc((size_t)TT*32*CC);
    float* TC   = alloc((size_t)CC*N4);
    float* bgAl = alloc((size_t)LL*CC*32);
    us16* Wgb  = (us16*)alloc((size_t)LL*KK*CC*CC/2);
    us16* Wt2b = (us16*)alloc((size_t)LL*CC*KDIM2/2);
    us16* Ut2  = (us16*)alloc((size_t)UR*CC/2);
    us16* AlTb = (us16*)alloc((size_t)LL*KK*32*32/2);
    (void)ws_size; (void)in_sizes; (void)n_in; (void)out_size;

    k_prep<<<(PTOT + 255)/256, 256, 0, stream>>>(Wg, Wt, A, imp, bg,
                                                 Wgb, Wt2b, AlTb, bgAl);

    float* hPrev = HT0; float* hNext = HT1;   // gcn_l writes h^l; fin reads h^8
    for (int l = 0; l < LL; l++) {
        if (l == 0) {
            k_gcn<1><<<TT + 8, 256, 0, stream>>>(
                x, lniw, lnib, Win, bin,
                TC, bt, ln2w, ln2b, hPrev,           // unused in FIRST
                Wgb, AlTb, bgAl, ln1w, ln1b,
                hPrev /* writes h^0 */, Ut2);
        } else {
            k_gcn<0><<<TT + 8, 256, 0, stream>>>(
                x, lniw, lnib, Win, bin,
                TC, bt + (size_t)(l-1)*CC,
                ln2w + (size_t)(l-1)*CC*VV, ln2b + (size_t)(l-1)*CC*VV,
                hPrev /* h^{l-1} residual */,
                Wgb + (size_t)l*KK*CC*CC,
                AlTb + (size_t)l*KK*32*32, bgAl + (size_t)l*CC*32,
                ln1w + (size_t)l*CC*VV, ln1b + (size_t)l*CC*VV,
                hNext /* writes h^l */, Ut2);
            float* tmp = hPrev; hPrev = hNext; hNext = tmp;
        }
        k_gemm2<<<dim3(64, 4), 256, 0, stream>>>(
            Wt2b + (size_t)l*CC*KDIM2, Ut2, TC);
    }
    k_fin<<<TT, 256, 0, stream>>>(TC, hPrev,
        bt + (size_t)(LL-1)*CC, ln2w + (size_t)(LL-1)*CC*VV, ln2b + (size_t)(LL-1)*CC*VV,
        Wout, bout, out);
}